// Round 4
// baseline (237.397 us; speedup 1.0000x reference)
//
#include <hip/hip_runtime.h>
#include <hip/hip_cooperative_groups.h>
#include <cstdint>

namespace cg = cooperative_groups;

#define BATCH 8
#define CIN 64
#define COUT 128
#define HH 32
#define WW 32
#define PH 34
#define PW 34

typedef int v4i __attribute__((ext_vector_type(4)));

// ---------------- workspace layout ----------------
// f32[0..511]   : partial absmax x (one per block)
// f32[512..583] : partial absmax w (blocks 0..71)
// byte 4096     : xpad  int8 NHWC-padded [8,34,34,64] = 591872 B
// byte 595968   : wfrag int8 MFMA-B-swizzled [9][8][64][16] = 73728 B
#define WS_PX 0
#define WS_PW 512
#define XPAD_OFF 4096
#define WFRAG_OFF (4096 + BATCH * PH * PW * CIN)

// phase-2 work split
#define QB_X 256
#define QB_W 72   // blocks [256,328)
#define QB_Z 66   // blocks [328,394)

__device__ __forceinline__ unsigned quantb(float v, float scale) {
    float q = rintf(v * scale);
    q = fminf(fmaxf(q, -128.0f), 127.0f);
    return ((unsigned)(int)q) & 255u;
}

__global__ __launch_bounds__(256, 2) void fused_all(const float* __restrict__ x,
                                                    const float* __restrict__ w,
                                                    const float* __restrict__ bias,
                                                    const float* __restrict__ Tf_in,
                                                    const float* __restrict__ Tw_in,
                                                    float* __restrict__ ws_f32,
                                                    uint8_t* __restrict__ xpad,
                                                    uint8_t* __restrict__ wfrag,
                                                    float* __restrict__ out) {
    cg::grid_group grid = cg::this_grid();
    const int blk = blockIdx.x;
    const int t = threadIdx.x;
    const int lane = t & 63;
    const int wave = t >> 6;

    __shared__ float sm[8];
    __shared__ unsigned lds[CIN * 9];   // 2304 B transpose buffer (phase 2)

    // ================= phase 1: absmax partials =================
    {
        const int tid = blk * 256 + t;                 // [0, 131072)
        float4 v = ((const float4*)x)[tid];
        float mx = fmaxf(fmaxf(fabsf(v.x), fabsf(v.y)), fmaxf(fabsf(v.z), fabsf(v.w)));
        float mw = 0.0f;
        if (tid < 18432) {                              // 73728 floats = 18432 float4
            float4 u = ((const float4*)w)[tid];
            mw = fmaxf(fmaxf(fabsf(u.x), fabsf(u.y)), fmaxf(fabsf(u.z), fabsf(u.w)));
        }
        #pragma unroll
        for (int off = 32; off > 0; off >>= 1) {
            mx = fmaxf(mx, __shfl_xor(mx, off, 64));
            mw = fmaxf(mw, __shfl_xor(mw, off, 64));
        }
        if (lane == 0) { sm[wave] = mx; sm[4 + wave] = mw; }
        __syncthreads();
        if (t == 0) {
            ws_f32[WS_PX + blk] = fmaxf(fmaxf(sm[0], sm[1]), fmaxf(sm[2], sm[3]));
            if (blk < 72)
                ws_f32[WS_PW + blk] = fmaxf(fmaxf(sm[4], sm[5]), fmaxf(sm[6], sm[7]));
        }
        __threadfence();
    }
    grid.sync();

    // ================= phase 2: reduce T + quantize/pack =================
    float Tf, Tw;
    {
        float mx = fmaxf(ws_f32[WS_PX + t], ws_f32[WS_PX + 256 + t]);
        float mw = (t < 72) ? ws_f32[WS_PW + t] : 0.0f;
        #pragma unroll
        for (int off = 32; off > 0; off >>= 1) {
            mx = fmaxf(mx, __shfl_xor(mx, off, 64));
            mw = fmaxf(mw, __shfl_xor(mw, off, 64));
        }
        __syncthreads();   // sm reuse hazard vs phase 1
        if (lane == 0) { sm[wave] = mx; sm[4 + wave] = mw; }
        __syncthreads();
        mx = fmaxf(fmaxf(sm[0], sm[1]), fmaxf(sm[2], sm[3]));
        mw = fmaxf(fmaxf(sm[4], sm[5]), fmaxf(sm[6], sm[7]));
        // match reference op order exactly
        float af = 0.95f * Tf_in[0];
        float bf = 0.05f * mx;
        Tf = af + bf;
        float aw = 0.95f * Tw_in[0];
        float bw = 0.05f * mw;
        Tw = aw + bw;
    }

    if (blk < QB_X) {
        // ---- x rows: coalesced float4 read, quantize, LDS transpose, NHWC write ----
        float scale = 127.0f / Tf;
        int b = blk >> 5, h = blk & 31;
        const float4* x4 = (const float4*)x;
        #pragma unroll
        for (int k = 0; k < 2; ++k) {
            int f = t + k * 256;            // [0,512): ci = f>>3, wq = f&7
            int ci = f >> 3, wq = f & 7;
            float4 v = x4[(b * CIN + ci) * 256 + h * 8 + wq];
            unsigned pack = quantb(v.x, scale) | (quantb(v.y, scale) << 8) |
                            (quantb(v.z, scale) << 16) | (quantb(v.w, scale) << 24);
            lds[ci * 9 + wq] = pack;
        }
        __syncthreads();
        const uint8_t* ldsb = (const uint8_t*)lds;
        unsigned* orow = (unsigned*)(xpad + (((b * PH) + (h + 1)) * PW + 1) * CIN);
        #pragma unroll
        for (int k = 0; k < 2; ++k) {
            int o = t + k * 256;            // [0,512): w = o>>4, c4 = o&15
            int ww_ = o >> 4, c4 = o & 15;
            unsigned d = (unsigned)ldsb[(c4 * 4 + 0) * 36 + ww_]
                       | ((unsigned)ldsb[(c4 * 4 + 1) * 36 + ww_] << 8)
                       | ((unsigned)ldsb[(c4 * 4 + 2) * 36 + ww_] << 16)
                       | ((unsigned)ldsb[(c4 * 4 + 3) * 36 + ww_] << 24);
            orow[o] = d;
        }
    } else if (blk < QB_X + QB_W) {
        // ---- weights -> MFMA-B fragment order ----
        float scale = 127.0f / Tw;
        int tid = (blk - QB_X) * 256 + t;
        int idx4 = tid * 4;
        int j0 = idx4 & 15;
        int ln = (idx4 >> 4) & 63;
        int f  = idx4 >> 10;          // tap*8 + g
        int g = f & 7;
        int tap = f >> 3;
        int kh = tap / 3, kw = tap - kh * 3;
        int co = g * 16 + (ln & 15);
        int ci0 = (ln >> 4) * 16 + j0;
        unsigned pack = 0;
        #pragma unroll
        for (int c = 0; c < 4; ++c) {
            float v = w[((co * CIN + ci0 + c) * 3 + kh) * 3 + kw];
            pack |= quantb(v, scale) << (8 * c);
        }
        ((unsigned*)wfrag)[tid] = pack;
    } else if (blk < QB_X + QB_W + QB_Z) {
        // ---- border zero-fill: 1056 pixels * 16 dwords ----
        int j = (blk - QB_X - QB_W) * 256 + t;
        int p = j >> 4, c4 = j & 15;
        int b = p / 132;
        int r = p - b * 132;
        int ih, iw;
        if (r < 34)      { ih = 0;           iw = r; }
        else if (r < 68) { ih = PH - 1;      iw = r - 34; }
        else if (r < 100){ ih = r - 68 + 1;  iw = 0; }
        else             { ih = r - 100 + 1; iw = PW - 1; }
        ((unsigned*)xpad)[((b * PH + ih) * PW + iw) * 16 + c4] = 0u;
    }
    __threadfence();
    grid.sync();

    // ================= phase 3: implicit-GEMM conv (mfma_i32_16x16x64_i8) =================
    {
        int nb = blk & 1;
        int mb = blk >> 1;
        int b = mb >> 5;
        int oh = mb & 31;
        int mt = wave & 1;
        int nh2 = wave >> 1;
        int row = lane & 15;
        int quad = lane >> 4;

        v4i acc[2];
        acc[0] = (v4i){0, 0, 0, 0};
        acc[1] = (v4i){0, 0, 0, 0};

        const uint8_t* xbase = xpad + (((b * PH + oh) * PW) + mt * 16 + row) * CIN + quad * 16;

        #pragma unroll
        for (int tp = 0; tp < 9; ++tp) {
            const int kh = tp / 3, kw = tp % 3;
            v4i afrag = *(const v4i*)(xbase + (kh * PW + kw) * CIN);
            #pragma unroll
            for (int nt = 0; nt < 2; ++nt) {
                int g = nb * 4 + nh2 * 2 + nt;
                v4i bfrag = *(const v4i*)(wfrag + (((tp * 8 + g) * 64) + lane) * 16);
                acc[nt] = __builtin_amdgcn_mfma_i32_16x16x64_i8(afrag, bfrag, acc[nt], 0, 0, 0);
            }
        }

        float s = (Tf / 127.0f) * (Tw / 127.0f);
        int ow0 = mt * 16 + quad * 4;
        #pragma unroll
        for (int nt = 0; nt < 2; ++nt) {
            int g = nb * 4 + nh2 * 2 + nt;
            int co = g * 16 + row;
            float bb = bias[co];
            float4 o;
            o.x = (float)acc[nt][0] * s + bb;
            o.y = (float)acc[nt][1] * s + bb;
            o.z = (float)acc[nt][2] * s + bb;
            o.w = (float)acc[nt][3] * s + bb;
            *(float4*)(out + (((b * COUT + co) * HH + oh) * WW) + ow0) = o;
        }
    }
}

extern "C" void kernel_launch(void* const* d_in, const int* in_sizes, int n_in,
                              void* d_out, int out_size, void* d_ws, size_t ws_size,
                              hipStream_t stream) {
    const float* x         = (const float*)d_in[0];
    const float* weight    = (const float*)d_in[1];
    const float* bias      = (const float*)d_in[2];
    const float* T_feature = (const float*)d_in[5];
    const float* T_weight  = (const float*)d_in[6];

    float*   ws_f32 = (float*)d_ws;
    uint8_t* xpad   = (uint8_t*)d_ws + XPAD_OFF;
    uint8_t* wfrag  = (uint8_t*)d_ws + WFRAG_OFF;
    float*   outp   = (float*)d_out;

    void* args[] = {(void*)&x, (void*)&weight, (void*)&bias, (void*)&T_feature,
                    (void*)&T_weight, (void*)&ws_f32, (void*)&xpad, (void*)&wfrag,
                    (void*)&outp};
    hipLaunchCooperativeKernel((const void*)fused_all, dim3(512), dim3(256),
                               args, 0, stream);
}

// Round 5
// 76.266 us; speedup vs baseline: 3.1127x; 3.1127x over previous
//
#include <hip/hip_runtime.h>
#include <cstdint>

#define BATCH 8
#define CIN 64
#define COUT 128
#define HH 32
#define WW 32
#define PH 34   // padded H
#define PW 34   // padded W

typedef int v4i __attribute__((ext_vector_type(4)));

// ---------------- workspace layout ----------------
// f32[0] Tf, f32[1] Tw, f32[16..175] partials (x: 16..143, w: 144..159)
// byte 4096   : xpad  int8 NHWC-padded [8,34,34,64] = 591872 B
// byte 595968 : wfrag int8 MFMA-B-swizzled [9][8][64][16] = 73728 B
#define WS_TF 0
#define WS_TW 1
#define WS_PART 16
#define XPAD_OFF 4096
#define WFRAG_OFF (4096 + BATCH * PH * PW * CIN)

// ---------- kernel 1: per-block absmax partials ----------
__global__ __launch_bounds__(256) void absmax_partial(const float* __restrict__ x,
                                                      const float* __restrict__ w,
                                                      float* __restrict__ partials) {
    float m = 0.0f;
    if (blockIdx.x < 128) {
        const float4* p = (const float4*)x;
        int base = blockIdx.x * 1024 + threadIdx.x;
        #pragma unroll
        for (int k = 0; k < 4; ++k) {
            float4 v = p[base + k * 256];
            m = fmaxf(m, fmaxf(fmaxf(fabsf(v.x), fabsf(v.y)), fmaxf(fabsf(v.z), fabsf(v.w))));
        }
    } else {
        const float4* p = (const float4*)w;
        int wb = blockIdx.x - 128;
        int base = wb * 1152 + threadIdx.x;
        int end = (wb + 1) * 1152;
        #pragma unroll
        for (int k = 0; k < 5; ++k) {
            int i = base + k * 256;
            if (i < end) {
                float4 v = p[i];
                m = fmaxf(m, fmaxf(fmaxf(fabsf(v.x), fabsf(v.y)), fmaxf(fabsf(v.z), fabsf(v.w))));
            }
        }
    }
    #pragma unroll
    for (int off = 32; off > 0; off >>= 1)
        m = fmaxf(m, __shfl_xor(m, off, 64));
    __shared__ float sm[4];
    int wave = threadIdx.x >> 6;
    if ((threadIdx.x & 63) == 0) sm[wave] = m;
    __syncthreads();
    if (threadIdx.x == 0)
        partials[WS_PART + blockIdx.x] = fmaxf(fmaxf(sm[0], sm[1]), fmaxf(sm[2], sm[3]));
}

__device__ __forceinline__ unsigned quantb(float v, float scale) {
    float q = rintf(v * scale);
    q = fminf(fmaxf(q, -128.0f), 127.0f);
    return ((unsigned)(int)q) & 255u;
}

// ---------- kernel 2: fused quantize+pack ----------
#define QB_X 256
#define QB_W 72
#define QB_Z 66
__global__ __launch_bounds__(256) void quant_pack(const float* __restrict__ x,
                                                  const float* __restrict__ w,
                                                  const float* __restrict__ Tf_in,
                                                  const float* __restrict__ Tw_in,
                                                  float* __restrict__ ws_f32,
                                                  uint8_t* __restrict__ xpad,
                                                  uint8_t* __restrict__ wfrag) {
    int blk = blockIdx.x;
    int t = threadIdx.x;
    int lane = t & 63;

    if (blk < QB_X) {
        // ---- x rows: coalesced float4 read, quantize, LDS transpose, NHWC write ----
        float m = fmaxf(ws_f32[WS_PART + lane], ws_f32[WS_PART + 64 + lane]);
        #pragma unroll
        for (int off = 32; off > 0; off >>= 1)
            m = fmaxf(m, __shfl_xor(m, off, 64));
        float a = 0.95f * Tf_in[0];
        float bt = 0.05f * m;
        float Tf = a + bt;
        if (blk == 0 && t == 0) ws_f32[WS_TF] = Tf;
        float scale = 127.0f / Tf;

        int b = blk >> 5, h = blk & 31;
        const float4* x4 = (const float4*)x;
        __shared__ unsigned lds[CIN * 9];   // pitch 9 dwords per ci
        #pragma unroll
        for (int k = 0; k < 2; ++k) {
            int f = t + k * 256;            // [0,512): ci = f>>3, wq = f&7
            int ci = f >> 3, wq = f & 7;
            float4 v = x4[(b * CIN + ci) * 256 + h * 8 + wq];
            unsigned pack = quantb(v.x, scale) | (quantb(v.y, scale) << 8) |
                            (quantb(v.z, scale) << 16) | (quantb(v.w, scale) << 24);
            lds[ci * 9 + wq] = pack;
        }
        __syncthreads();
        const uint8_t* ldsb = (const uint8_t*)lds;
        unsigned* orow = (unsigned*)(xpad + (((b * PH) + (h + 1)) * PW + 1) * CIN);
        #pragma unroll
        for (int k = 0; k < 2; ++k) {
            int o = t + k * 256;            // [0,512): w = o>>4, c4 = o&15
            int ww_ = o >> 4, c4 = o & 15;
            unsigned d = (unsigned)ldsb[(c4 * 4 + 0) * 36 + ww_]
                       | ((unsigned)ldsb[(c4 * 4 + 1) * 36 + ww_] << 8)
                       | ((unsigned)ldsb[(c4 * 4 + 2) * 36 + ww_] << 16)
                       | ((unsigned)ldsb[(c4 * 4 + 3) * 36 + ww_] << 24);
            orow[o] = d;
        }
    } else if (blk < QB_X + QB_W) {
        // ---- weights -> MFMA-B fragment order ----
        float m = ws_f32[WS_PART + 128 + (lane & 15)];
        #pragma unroll
        for (int off = 32; off > 0; off >>= 1)
            m = fmaxf(m, __shfl_xor(m, off, 64));
        float a = 0.95f * Tw_in[0];
        float bt = 0.05f * m;
        float Tw = a + bt;
        if (blk == QB_X && t == 0) ws_f32[WS_TW] = Tw;
        float scale = 127.0f / Tw;

        int tid = (blk - QB_X) * 256 + t;
        int idx4 = tid * 4;
        int j0 = idx4 & 15;
        int ln = (idx4 >> 4) & 63;
        int f  = idx4 >> 10;          // tap*8 + g
        int g = f & 7;
        int tap = f >> 3;
        int kh = tap / 3, kw = tap - kh * 3;
        int co = g * 16 + (ln & 15);
        int ci0 = (ln >> 4) * 16 + j0;
        unsigned pack = 0;
        #pragma unroll
        for (int c = 0; c < 4; ++c) {
            float v = w[((co * CIN + ci0 + c) * 3 + kh) * 3 + kw];
            pack |= quantb(v, scale) << (8 * c);
        }
        ((unsigned*)wfrag)[tid] = pack;
    } else {
        // ---- border zero-fill: 1056 pixels * 16 dwords ----
        int j = (blk - QB_X - QB_W) * 256 + t;
        int p = j >> 4, c4 = j & 15;
        int b = p / 132;
        int r = p - b * 132;
        int ih, iw;
        if (r < 34)      { ih = 0;           iw = r; }
        else if (r < 68) { ih = PH - 1;      iw = r - 34; }
        else if (r < 100){ ih = r - 68 + 1;  iw = 0; }
        else             { ih = r - 100 + 1; iw = PW - 1; }
        ((unsigned*)xpad)[((b * PH + ih) * PW + iw) * 16 + c4] = 0u;
    }
}

// ---------- kernel 3: implicit-GEMM conv, 1024 blocks (4/CU, 16 waves/CU) ----------
// blk: nb = blk&1 (cout half), mt = (blk>>1)&1 (pixel half), rt = blk>>2 -> (b,oh)
// wave: one 16-pixel x 16-cout tile; g = nb*4 + wave
__global__ __launch_bounds__(256, 4) void conv_mfma(const uint8_t* __restrict__ xpad,
                                                    const uint8_t* __restrict__ wfrag,
                                                    const float* __restrict__ bias,
                                                    const float* __restrict__ ws_f32,
                                                    float* __restrict__ out) {
    int blk = blockIdx.x;
    int nb = blk & 1;
    int mt = (blk >> 1) & 1;
    int rt = blk >> 2;
    int b = rt >> 5;
    int oh = rt & 31;
    int wave = threadIdx.x >> 6;
    int lane = threadIdx.x & 63;
    int row = lane & 15;
    int quad = lane >> 4;
    int g = nb * 4 + wave;

    v4i acc = (v4i){0, 0, 0, 0};

    const uint8_t* xbase = xpad + (((b * PH + oh) * PW) + mt * 16 + row) * CIN + quad * 16;
    const uint8_t* wbase = wfrag + (g * 64 + lane) * 16;

    #pragma unroll
    for (int tp = 0; tp < 9; ++tp) {
        const int kh = tp / 3, kw = tp % 3;
        v4i afrag = *(const v4i*)(xbase + (kh * PW + kw) * CIN);
        v4i bfrag = *(const v4i*)(wbase + tp * 8 * 64 * 16);
        acc = __builtin_amdgcn_mfma_i32_16x16x64_i8(afrag, bfrag, acc, 0, 0, 0);
    }

    float Tf = ws_f32[WS_TF];
    float Tw = ws_f32[WS_TW];
    float s = (Tf / 127.0f) * (Tw / 127.0f);
    int ow0 = mt * 16 + quad * 4;
    int co = g * 16 + row;
    float bb = bias[co];
    float4 o;
    o.x = (float)acc[0] * s + bb;
    o.y = (float)acc[1] * s + bb;
    o.z = (float)acc[2] * s + bb;
    o.w = (float)acc[3] * s + bb;
    *(float4*)(out + (((b * COUT + co) * HH + oh) * WW) + ow0) = o;
}

extern "C" void kernel_launch(void* const* d_in, const int* in_sizes, int n_in,
                              void* d_out, int out_size, void* d_ws, size_t ws_size,
                              hipStream_t stream) {
    const float* x         = (const float*)d_in[0];
    const float* weight    = (const float*)d_in[1];
    const float* bias      = (const float*)d_in[2];
    const float* T_feature = (const float*)d_in[5];
    const float* T_weight  = (const float*)d_in[6];

    float*   ws_f32 = (float*)d_ws;
    uint8_t* xpad   = (uint8_t*)d_ws + XPAD_OFF;
    uint8_t* wfrag  = (uint8_t*)d_ws + WFRAG_OFF;

    absmax_partial<<<144, 256, 0, stream>>>(x, weight, ws_f32);
    quant_pack<<<QB_X + QB_W + QB_Z, 256, 0, stream>>>(x, weight, T_feature, T_weight,
                                                       ws_f32, xpad, wfrag);
    conv_mfma<<<1024, 256, 0, stream>>>(xpad, wfrag, bias, ws_f32, (float*)d_out);
}

// Round 7
// 74.748 us; speedup vs baseline: 3.1760x; 1.0203x over previous
//
#include <hip/hip_runtime.h>
#include <cstdint>

#define BATCH 8
#define CIN 64
#define COUT 128
#define HH 32
#define WW 32
#define PH 34   // padded H
#define PW 34   // padded W

typedef int v4i __attribute__((ext_vector_type(4)));
typedef float v4f __attribute__((ext_vector_type(4)));

// ---------------- workspace layout ----------------
// f32[0] Tf, f32[1] Tw, f32[16..175] partials (x: 16..143, w: 144..159)
// byte 4096   : xpad  int8 NHWC-padded [8,34,34,64] = 591872 B
// byte 595968 : wfrag int8 MFMA-B-swizzled [9][8][64][16] = 73728 B
#define WS_TF 0
#define WS_TW 1
#define WS_PART 16
#define XPAD_OFF 4096
#define WFRAG_OFF (4096 + BATCH * PH * PW * CIN)

// ---------- kernel 1: absmax partials + xpad border zero-fill ----------
// blocks 0..127  : x absmax partials
// blocks 128..143: w absmax partials
// blocks 144..209: xpad border zero-fill (independent of absmax)
__global__ __launch_bounds__(256) void absmax_zfill(const float* __restrict__ x,
                                                    const float* __restrict__ w,
                                                    float* __restrict__ partials,
                                                    uint8_t* __restrict__ xpad) {
    int blk = blockIdx.x;
    int t = threadIdx.x;

    if (blk >= 144) {
        // ---- border zero-fill: 1056 pixels * 16 dwords = 16896 dwords ----
        int j = (blk - 144) * 256 + t;
        int p = j >> 4, c4 = j & 15;
        int b = p / 132;
        int r = p - b * 132;
        int ih, iw;
        if (r < 34)      { ih = 0;           iw = r; }
        else if (r < 68) { ih = PH - 1;      iw = r - 34; }
        else if (r < 100){ ih = r - 68 + 1;  iw = 0; }
        else             { ih = r - 100 + 1; iw = PW - 1; }
        ((unsigned*)xpad)[((b * PH + ih) * PW + iw) * 16 + c4] = 0u;
        return;
    }

    float m = 0.0f;
    if (blk < 128) {
        const float4* p = (const float4*)x;
        int base = blk * 1024 + t;
        #pragma unroll
        for (int k = 0; k < 4; ++k) {
            float4 v = p[base + k * 256];
            m = fmaxf(m, fmaxf(fmaxf(fabsf(v.x), fabsf(v.y)), fmaxf(fabsf(v.z), fabsf(v.w))));
        }
    } else {
        const float4* p = (const float4*)w;
        int wb = blk - 128;
        int base = wb * 1152 + t;
        int end = (wb + 1) * 1152;
        #pragma unroll
        for (int k = 0; k < 5; ++k) {
            int i = base + k * 256;
            if (i < end) {
                float4 v = p[i];
                m = fmaxf(m, fmaxf(fmaxf(fabsf(v.x), fabsf(v.y)), fmaxf(fabsf(v.z), fabsf(v.w))));
            }
        }
    }
    #pragma unroll
    for (int off = 32; off > 0; off >>= 1)
        m = fmaxf(m, __shfl_xor(m, off, 64));
    __shared__ float sm[4];
    int wave = t >> 6;
    if ((t & 63) == 0) sm[wave] = m;
    __syncthreads();
    if (t == 0)
        partials[WS_PART + blk] = fmaxf(fmaxf(sm[0], sm[1]), fmaxf(sm[2], sm[3]));
}

__device__ __forceinline__ unsigned quantb(float v, float scale) {
    float q = rintf(v * scale);
    q = fminf(fmaxf(q, -128.0f), 127.0f);
    return ((unsigned)(int)q) & 255u;
}

// ---------- kernel 2: fused quantize+pack (x interior + weights) ----------
#define QB_X 256
#define QB_W 72
__global__ __launch_bounds__(256) void quant_pack(const float* __restrict__ x,
                                                  const float* __restrict__ w,
                                                  const float* __restrict__ Tf_in,
                                                  const float* __restrict__ Tw_in,
                                                  float* __restrict__ ws_f32,
                                                  uint8_t* __restrict__ xpad,
                                                  uint8_t* __restrict__ wfrag) {
    int blk = blockIdx.x;
    int t = threadIdx.x;
    int lane = t & 63;

    if (blk < QB_X) {
        // ---- x rows: coalesced float4 read, quantize, LDS transpose, NHWC write ----
        float m = fmaxf(ws_f32[WS_PART + lane], ws_f32[WS_PART + 64 + lane]);
        #pragma unroll
        for (int off = 32; off > 0; off >>= 1)
            m = fmaxf(m, __shfl_xor(m, off, 64));
        float a = 0.95f * Tf_in[0];
        float bt = 0.05f * m;
        float Tf = a + bt;
        if (blk == 0 && t == 0) ws_f32[WS_TF] = Tf;
        float scale = 127.0f / Tf;

        int b = blk >> 5, h = blk & 31;
        const float4* x4 = (const float4*)x;
        __shared__ unsigned lds[CIN * 9];   // pitch 9 dwords per ci
        #pragma unroll
        for (int k = 0; k < 2; ++k) {
            int f = t + k * 256;            // [0,512): ci = f>>3, wq = f&7
            int ci = f >> 3, wq = f & 7;
            float4 v = x4[(b * CIN + ci) * 256 + h * 8 + wq];
            unsigned pack = quantb(v.x, scale) | (quantb(v.y, scale) << 8) |
                            (quantb(v.z, scale) << 16) | (quantb(v.w, scale) << 24);
            lds[ci * 9 + wq] = pack;
        }
        __syncthreads();
        const uint8_t* ldsb = (const uint8_t*)lds;
        unsigned* orow = (unsigned*)(xpad + (((b * PH) + (h + 1)) * PW + 1) * CIN);
        #pragma unroll
        for (int k = 0; k < 2; ++k) {
            int o = t + k * 256;            // [0,512): w = o>>4, c4 = o&15
            int ww_ = o >> 4, c4 = o & 15;
            unsigned d = (unsigned)ldsb[(c4 * 4 + 0) * 36 + ww_]
                       | ((unsigned)ldsb[(c4 * 4 + 1) * 36 + ww_] << 8)
                       | ((unsigned)ldsb[(c4 * 4 + 2) * 36 + ww_] << 16)
                       | ((unsigned)ldsb[(c4 * 4 + 3) * 36 + ww_] << 24);
            orow[o] = d;
        }
    } else {
        // ---- weights -> MFMA-B fragment order ----
        float m = ws_f32[WS_PART + 128 + (lane & 15)];
        #pragma unroll
        for (int off = 32; off > 0; off >>= 1)
            m = fmaxf(m, __shfl_xor(m, off, 64));
        float a = 0.95f * Tw_in[0];
        float bt = 0.05f * m;
        float Tw = a + bt;
        if (blk == QB_X && t == 0) ws_f32[WS_TW] = Tw;
        float scale = 127.0f / Tw;

        int tid = (blk - QB_X) * 256 + t;
        int idx4 = tid * 4;
        int j0 = idx4 & 15;
        int ln = (idx4 >> 4) & 63;
        int f  = idx4 >> 10;          // tap*8 + g
        int g = f & 7;
        int tap = f >> 3;
        int kh = tap / 3, kw = tap - kh * 3;
        int co = g * 16 + (ln & 15);
        int ci0 = (ln >> 4) * 16 + j0;
        unsigned pack = 0;
        #pragma unroll
        for (int c = 0; c < 4; ++c) {
            float v = w[((co * CIN + ci0 + c) * 3 + kh) * 3 + kw];
            pack |= quantb(v, scale) << (8 * c);
        }
        ((unsigned*)wfrag)[tid] = pack;
    }
}

// ---------- kernel 3: implicit-GEMM conv, 512 blocks (2/CU) ----------
__global__ __launch_bounds__(256, 2) void conv_mfma(const uint8_t* __restrict__ xpad,
                                                    const uint8_t* __restrict__ wfrag,
                                                    const float* __restrict__ bias,
                                                    const float* __restrict__ ws_f32,
                                                    float* __restrict__ out) {
    int blk = blockIdx.x;         // 512: nb = blk&1 (cout half), mb = blk>>1
    int nb = blk & 1;
    int mb = blk >> 1;
    int b = mb >> 5;
    int oh = mb & 31;
    int wave = threadIdx.x >> 6;
    int lane = threadIdx.x & 63;
    int mt = wave & 1;            // pixel half (16 pixels)
    int nh2 = wave >> 1;          // cout sub-half
    int row = lane & 15;
    int quad = lane >> 4;

    v4i acc[2];
    acc[0] = (v4i){0, 0, 0, 0};
    acc[1] = (v4i){0, 0, 0, 0};

    const uint8_t* xbase = xpad + (((b * PH + oh) * PW) + mt * 16 + row) * CIN + quad * 16;

    #pragma unroll
    for (int tp = 0; tp < 9; ++tp) {
        const int kh = tp / 3, kw = tp % 3;
        v4i afrag = *(const v4i*)(xbase + (kh * PW + kw) * CIN);
        #pragma unroll
        for (int nt = 0; nt < 2; ++nt) {
            int g = nb * 4 + nh2 * 2 + nt;
            v4i bfrag = *(const v4i*)(wfrag + (((tp * 8 + g) * 64) + lane) * 16);
            acc[nt] = __builtin_amdgcn_mfma_i32_16x16x64_i8(afrag, bfrag, acc[nt], 0, 0, 0);
        }
    }

    float Tf = ws_f32[WS_TF];
    float Tw = ws_f32[WS_TW];
    float s = (Tf / 127.0f) * (Tw / 127.0f);
    int ow0 = mt * 16 + quad * 4;
    #pragma unroll
    for (int nt = 0; nt < 2; ++nt) {
        int g = nb * 4 + nh2 * 2 + nt;
        int co = g * 16 + row;
        float bb = bias[co];
        v4f o;
        o.x = (float)acc[nt][0] * s + bb;
        o.y = (float)acc[nt][1] * s + bb;
        o.z = (float)acc[nt][2] * s + bb;
        o.w = (float)acc[nt][3] * s + bb;
        __builtin_nontemporal_store(o, (v4f*)(out + (((b * COUT + co) * HH + oh) * WW) + ow0));
    }
}

extern "C" void kernel_launch(void* const* d_in, const int* in_sizes, int n_in,
                              void* d_out, int out_size, void* d_ws, size_t ws_size,
                              hipStream_t stream) {
    const float* x         = (const float*)d_in[0];
    const float* weight    = (const float*)d_in[1];
    const float* bias      = (const float*)d_in[2];
    const float* T_feature = (const float*)d_in[5];
    const float* T_weight  = (const float*)d_in[6];

    float*   ws_f32 = (float*)d_ws;
    uint8_t* xpad   = (uint8_t*)d_ws + XPAD_OFF;
    uint8_t* wfrag  = (uint8_t*)d_ws + WFRAG_OFF;

    absmax_zfill<<<210, 256, 0, stream>>>(x, weight, ws_f32, xpad);
    quant_pack<<<QB_X + QB_W, 256, 0, stream>>>(x, weight, T_feature, T_weight,
                                                ws_f32, xpad, wfrag);
    conv_mfma<<<512, 256, 0, stream>>>(xpad, wfrag, bias, ws_f32, (float*)d_out);
}